// Round 2
// baseline (597.435 us; speedup 1.0000x reference)
//
#include <hip/hip_runtime.h>
#include <stdint.h>

// Attention_45148696216940: B=4, C=256, H=W=64 -> N=4096
// Pipeline (all bf16 MFMA 16x16x32, fp32 accum):
//   k0: X[b,c,n] f32 -> XT[b,n,c] bf16
//   k1: QT[b,n,c]=(Wq X + bq)/16, KT[b,n,c]=Wk X + bk (bf16), V[b,c,n]=Wv X + bv (bf16)
//   k2: column-stats of S^T (softmax over i): M[b,j], L[b,j]
//   k2b: V[c,j] *= 1/L[j]
//   k3: recompute S^T, P=exp(s-M[j]), PV -> atomicAdd OT[b,i,c] f32 (j split in 2)
//   k4: out = Wp . O + bp with split-bf16 (hi/lo) for accuracy
//
// MFMA conventions (self-consistent k-slot maps cancel per-GEMM):
//   A row m = lane&15, B col n = lane&15, k-slot e (0..7) of lane-group g=lane>>4:
//   k = 32*cc + 8*g + e  (contiguous -> single b128 from row-major storage)
//   C/D (HW-verified): col = lane&15, row = 4*(lane>>4) + reg

#define DI __device__ __forceinline__
typedef __attribute__((ext_vector_type(4))) float f32x4;
typedef __attribute__((ext_vector_type(8))) short s16x8;
typedef __attribute__((ext_vector_type(4))) short s16x4;
typedef __attribute__((ext_vector_type(4))) unsigned short u16x4;

constexpr int C = 256;
constexpr int N = 4096;

DI unsigned short f2bf(float f) {
  unsigned int u = __float_as_uint(f);
  u += 0x7FFFu + ((u >> 16) & 1u);   // RNE
  return (unsigned short)(u >> 16);
}
DI float bf2f(unsigned short s) { return __uint_as_float(((unsigned int)s) << 16); }

DI f32x4 mfma16(s16x8 a, s16x8 b, f32x4 c) {
  return __builtin_amdgcn_mfma_f32_16x16x32_bf16(a, b, c, 0, 0, 0);
}

// ---------------- k0: transpose X [b,c,n] f32 -> XT [b,n,c] bf16 ----------------
__global__ __launch_bounds__(256) void k0_transpose(const float* __restrict__ X,
                                                    unsigned short* __restrict__ XT) {
  __shared__ float tile[64 * 65];  // pad 65 -> conflict-free-ish both directions
  int t = threadIdx.x;
  int wg = blockIdx.x;
  int b = wg >> 8, rem = wg & 255;
  int c0 = (rem >> 6) * 64, n0 = (rem & 63) * 64;
  const float* xb = X + (size_t)b * C * N;
  int cl = t >> 2, ng = (t & 3) * 16;
#pragma unroll
  for (int k = 0; k < 4; ++k) {
    f32x4 v = *(const f32x4*)(xb + (size_t)(c0 + cl) * N + n0 + ng + k * 4);
#pragma unroll
    for (int e = 0; e < 4; ++e) tile[cl * 65 + ng + k * 4 + e] = v[e];
  }
  __syncthreads();
  int nl = t >> 2, cg = (t & 3) * 16;
  unsigned short* xtb = XT + (size_t)b * N * C;
  s16x8 o0v, o1v;
#pragma unroll
  for (int j = 0; j < 8; ++j) o0v[j] = (short)f2bf(tile[(cg + j) * 65 + nl]);
#pragma unroll
  for (int j = 0; j < 8; ++j) o1v[j] = (short)f2bf(tile[(cg + 8 + j) * 65 + nl]);
  *(s16x8*)(xtb + (size_t)(n0 + nl) * C + c0 + cg) = o0v;
  *(s16x8*)(xtb + (size_t)(n0 + nl) * C + c0 + cg + 8) = o1v;
}

// ---------------- k1: QKV projections ----------------
__global__ __launch_bounds__(256) void k1_qkv(
    const unsigned short* __restrict__ XT,
    const float* __restrict__ wq, const float* __restrict__ bq,
    const float* __restrict__ wk, const float* __restrict__ bk,
    const float* __restrict__ wv, const float* __restrict__ bv,
    unsigned short* __restrict__ QT, unsigned short* __restrict__ KT,
    unsigned short* __restrict__ V) {
  int t = threadIdx.x, lane = t & 63, w = t >> 6, l15 = lane & 15, g = lane >> 4;
  int wg = blockIdx.x, b = wg >> 6, nb = wg & 63;
  int n0 = nb * 64;
  const unsigned short* xtb = XT + (size_t)b * N * C;
  const float* Ws[3] = {wq, wk, wv};
  const float* Bs[3] = {bq, bk, bv};
#pragma unroll
  for (int np = 0; np < 2; ++np) {
    s16x8 xf[2][8];
#pragma unroll
    for (int n2 = 0; n2 < 2; ++n2)
#pragma unroll
      for (int cc = 0; cc < 8; ++cc)
        xf[n2][cc] = *(const s16x8*)(xtb + (size_t)(n0 + np * 32 + n2 * 16 + l15) * C + cc * 32 + g * 8);
#pragma unroll
    for (int ty = 0; ty < 3; ++ty) {
#pragma unroll
      for (int ot = 0; ot < 4; ++ot) {
        int o0 = w * 64 + ot * 16;
        f32x4 bias = *(const f32x4*)(Bs[ty] + o0 + g * 4);
        s16x8 wf[8];
#pragma unroll
        for (int cc = 0; cc < 8; ++cc) {
          const float* wr = Ws[ty] + (size_t)(o0 + l15) * C + cc * 32 + g * 8;
          f32x4 a = *(const f32x4*)wr;
          f32x4 b2 = *(const f32x4*)(wr + 4);
          s16x8 f;
#pragma unroll
          for (int e = 0; e < 4; ++e) { f[e] = (short)f2bf(a[e]); f[e + 4] = (short)f2bf(b2[e]); }
          wf[cc] = f;
        }
#pragma unroll
        for (int n2 = 0; n2 < 2; ++n2) {
          f32x4 D = {0.f, 0.f, 0.f, 0.f};
#pragma unroll
          for (int cc = 0; cc < 8; ++cc) D = mfma16(wf[cc], xf[n2][cc], D);
          int n = n0 + np * 32 + n2 * 16 + l15;
          if (ty < 2) {
            float sc = (ty == 0) ? 0.0625f : 1.0f;  // fold C^-0.5 into Q
            s16x4 pk;
#pragma unroll
            for (int r = 0; r < 4; ++r) pk[r] = (short)f2bf((D[r] + bias[r]) * sc);
            unsigned short* dst = (ty == 0 ? QT : KT) + (size_t)b * N * C + (size_t)n * C + o0 + g * 4;
            *(s16x4*)dst = pk;
          } else {
#pragma unroll
            for (int r = 0; r < 4; ++r)
              V[(size_t)b * C * N + (size_t)(o0 + g * 4 + r) * N + n] = f2bf(D[r] + bias[r]);
          }
        }
      }
    }
  }
}

// ---------------- k2: per-column (j) softmax stats over i ----------------
__global__ __launch_bounds__(256, 2) void k2_stats(
    const unsigned short* __restrict__ QT, const unsigned short* __restrict__ KT,
    float* __restrict__ M, float* __restrict__ L) {
  __shared__ float sm[4][32], sl[4][32];
  int t = threadIdx.x, lane = t & 63, w = t >> 6, l15 = lane & 15, g = lane >> 4;
  int wg = blockIdx.x, b = wg >> 7, jb = wg & 127;
  const unsigned short* qtb = QT + (size_t)b * N * C;
  const unsigned short* ktb = KT + (size_t)b * N * C;
  s16x8 kf[2][8];
#pragma unroll
  for (int jt = 0; jt < 2; ++jt)
#pragma unroll
    for (int cc = 0; cc < 8; ++cc)
      kf[jt][cc] = *(const s16x8*)(ktb + (size_t)(jb * 32 + jt * 16 + l15) * C + cc * 32 + g * 8);
  float m0[4], l0[4], m1[4], l1[4];
#pragma unroll
  for (int r = 0; r < 4; ++r) { m0[r] = -3e38f; l0[r] = 0.f; m1[r] = -3e38f; l1[r] = 0.f; }
  for (int ic = 0; ic < 64; ++ic) {
    int i0 = w * 1024 + ic * 16;
    s16x8 qf[8];
#pragma unroll
    for (int cc = 0; cc < 8; ++cc)
      qf[cc] = *(const s16x8*)(qtb + (size_t)(i0 + l15) * C + cc * 32 + g * 8);
    f32x4 D0 = {0.f, 0.f, 0.f, 0.f}, D1 = {0.f, 0.f, 0.f, 0.f};
#pragma unroll
    for (int cc = 0; cc < 8; ++cc) {
      D0 = mfma16(kf[0][cc], qf[cc], D0);
      D1 = mfma16(kf[1][cc], qf[cc], D1);
    }
#pragma unroll
    for (int r = 0; r < 4; ++r) {
      float s = D0[r];
      float mn = fmaxf(m0[r], s);
      l0[r] = l0[r] * __expf(m0[r] - mn) + __expf(s - mn);
      m0[r] = mn;
      s = D1[r];
      mn = fmaxf(m1[r], s);
      l1[r] = l1[r] * __expf(m1[r] - mn) + __expf(s - mn);
      m1[r] = mn;
    }
  }
  // reduce over the 16 lanes (i-columns) of each lane-group
#pragma unroll
  for (int off = 1; off < 16; off <<= 1) {
#pragma unroll
    for (int r = 0; r < 4; ++r) {
      float om = __shfl_xor(m0[r], off); float ol = __shfl_xor(l0[r], off);
      float mn = fmaxf(m0[r], om);
      l0[r] = l0[r] * __expf(m0[r] - mn) + ol * __expf(om - mn); m0[r] = mn;
      om = __shfl_xor(m1[r], off); ol = __shfl_xor(l1[r], off);
      mn = fmaxf(m1[r], om);
      l1[r] = l1[r] * __expf(m1[r] - mn) + ol * __expf(om - mn); m1[r] = mn;
    }
  }
  if (l15 == 0) {
#pragma unroll
    for (int r = 0; r < 4; ++r) {
      sm[w][g * 4 + r] = m0[r]; sl[w][g * 4 + r] = l0[r];
      sm[w][16 + g * 4 + r] = m1[r]; sl[w][16 + g * 4 + r] = l1[r];
    }
  }
  __syncthreads();
  if (t < 32) {
    float mm = sm[0][t], ll = sl[0][t];
#pragma unroll
    for (int ww = 1; ww < 4; ++ww) {
      float om = sm[ww][t], ol = sl[ww][t];
      float mn = fmaxf(mm, om);
      ll = ll * __expf(mm - mn) + ol * __expf(om - mn);
      mm = mn;
    }
    M[(size_t)b * N + jb * 32 + t] = mm;
    L[(size_t)b * N + jb * 32 + t] = ll;
  }
}

// ---------------- k2b: V[c,j] *= 1/L[j] ----------------
__global__ __launch_bounds__(256) void k2b_scale_v(unsigned short* __restrict__ V,
                                                   const float* __restrict__ L) {
  int idx4 = (blockIdx.x * 256 + threadIdx.x) * 4;  // over B*C*N
  int b = idx4 >> 20, n4 = idx4 & (N - 1);
  u16x4 v = *(u16x4*)(V + (size_t)idx4);
  f32x4 lv = *(const f32x4*)(L + (size_t)b * N + n4);
  u16x4 o;
#pragma unroll
  for (int e = 0; e < 4; ++e) o[e] = f2bf(bf2f(v[e]) / lv[e]);
  *(u16x4*)(V + (size_t)idx4) = o;
}

// ---------------- k3: attention core (recompute S^T, P=exp(s-m), PV) ----------------
__global__ __launch_bounds__(256, 2) void k3_attn(
    const unsigned short* __restrict__ QT, const unsigned short* __restrict__ KT,
    const unsigned short* __restrict__ V, const float* __restrict__ M,
    float* __restrict__ OT) {
  __shared__ short pl[64 * 36];  // P tile [64 i][32 j], row stride 36 shorts (72B, pad 4)
  int t = threadIdx.x, lane = t & 63, w = t >> 6, l15 = lane & 15, g = lane >> 4;
  int wg = blockIdx.x, b = wg >> 7, r2 = wg & 127, ib = r2 >> 1, jh = r2 & 1;
  int jt = w & 1, itp = w >> 1, cw = w * 64;
  const unsigned short* qtb = QT + (size_t)b * N * C;
  const unsigned short* ktb = KT + (size_t)b * N * C;
  const unsigned short* vb = V + (size_t)b * C * N;
  const float* mb = M + (size_t)b * N;
  float* otb = OT + (size_t)b * N * C;
  s16x8 qf[2][8];
#pragma unroll
  for (int itt = 0; itt < 2; ++itt)
#pragma unroll
    for (int cc = 0; cc < 8; ++cc)
      qf[itt][cc] = *(const s16x8*)(qtb + (size_t)(ib * 64 + (itp * 2 + itt) * 16 + l15) * C + cc * 32 + g * 8);
  f32x4 acc[4][4];
#pragma unroll
  for (int a = 0; a < 4; ++a)
#pragma unroll
    for (int bq2 = 0; bq2 < 4; ++bq2) acc[a][bq2] = (f32x4){0.f, 0.f, 0.f, 0.f};

  for (int jc = jh * 64; jc < jh * 64 + 64; ++jc) {
    int J0 = jc * 32;
    f32x4 mv = *(const f32x4*)(mb + J0 + jt * 16 + g * 4);
    f32x4 D0 = {0.f, 0.f, 0.f, 0.f}, D1 = {0.f, 0.f, 0.f, 0.f};
#pragma unroll
    for (int cc = 0; cc < 8; ++cc) {
      s16x8 kfr = *(const s16x8*)(ktb + (size_t)(J0 + jt * 16 + l15) * C + cc * 32 + g * 8);
      D0 = mfma16(kfr, qf[0][cc], D0);
      D1 = mfma16(kfr, qf[1][cc], D1);
    }
    s16x4 p0, p1;
#pragma unroll
    for (int r = 0; r < 4; ++r) {
      p0[r] = (short)f2bf(__expf(D0[r] - mv[r]));
      p1[r] = (short)f2bf(__expf(D1[r] - mv[r]));
    }
    *(s16x4*)&pl[(itp * 32 + l15) * 36 + jt * 16 + g * 4] = p0;
    *(s16x4*)&pl[(itp * 32 + 16 + l15) * 36 + jt * 16 + g * 4] = p1;
    __syncthreads();
    s16x8 pf[4];
#pragma unroll
    for (int it = 0; it < 4; ++it) {
      s16x4 a = *(const s16x4*)&pl[(it * 16 + l15) * 36 + g * 8];
      s16x4 c4 = *(const s16x4*)&pl[(it * 16 + l15) * 36 + g * 8 + 4];
      pf[it] = __builtin_shufflevector(a, c4, 0, 1, 2, 3, 4, 5, 6, 7);
    }
#pragma unroll
    for (int ct = 0; ct < 4; ++ct) {
      s16x8 vf = *(const s16x8*)(vb + (size_t)(cw + ct * 16 + l15) * N + J0 + g * 8);
#pragma unroll
      for (int it = 0; it < 4; ++it) acc[ct][it] = mfma16(vf, pf[it], acc[ct][it]);
    }
    __syncthreads();
  }
#pragma unroll
  for (int ct = 0; ct < 4; ++ct)
#pragma unroll
    for (int it = 0; it < 4; ++it)
#pragma unroll
      for (int r = 0; r < 4; ++r)
        atomicAdd(&otb[(size_t)(ib * 64 + it * 16 + l15) * C + cw + ct * 16 + g * 4 + r],
                  acc[ct][it][r]);
}

// ---------------- k4: proj with split-bf16 (hi/lo) ----------------
__global__ __launch_bounds__(256) void k4_proj(const float* __restrict__ OT,
                                               const float* __restrict__ wp,
                                               const float* __restrict__ bp,
                                               float* __restrict__ OUT) {
  int t = threadIdx.x, lane = t & 63, w = t >> 6, l15 = lane & 15, g = lane >> 4;
  int wg = blockIdx.x, b = wg >> 6, nb = wg & 63;
  const float* otb = OT + (size_t)b * N * C;
  float* ob = OUT + (size_t)b * (size_t)C * N;
  for (int nt = 0; nt < 4; ++nt) {
    s16x8 xh[8], xl[8];
#pragma unroll
    for (int cc = 0; cc < 8; ++cc) {
      const float* p = otb + (size_t)(nb * 64 + nt * 16 + l15) * C + cc * 32 + g * 8;
      f32x4 a = *(const f32x4*)p;
      f32x4 b2 = *(const f32x4*)(p + 4);
      s16x8 h, lo;
#pragma unroll
      for (int e = 0; e < 4; ++e) {
        unsigned short hh = f2bf(a[e]); h[e] = (short)hh; lo[e] = (short)f2bf(a[e] - bf2f(hh));
        unsigned short h2 = f2bf(b2[e]); h[e + 4] = (short)h2; lo[e + 4] = (short)f2bf(b2[e] - bf2f(h2));
      }
      xh[cc] = h; xl[cc] = lo;
    }
#pragma unroll
    for (int ot = 0; ot < 4; ++ot) {
      int o0 = w * 64 + ot * 16;
      f32x4 bias = *(const f32x4*)(bp + o0 + g * 4);
      f32x4 D = {0.f, 0.f, 0.f, 0.f};
#pragma unroll
      for (int cc = 0; cc < 8; ++cc) {
        const float* wr = wp + (size_t)(o0 + l15) * C + cc * 32 + g * 8;
        f32x4 a = *(const f32x4*)wr;
        f32x4 b2 = *(const f32x4*)(wr + 4);
        s16x8 h, lo;
#pragma unroll
        for (int e = 0; e < 4; ++e) {
          unsigned short hh = f2bf(a[e]); h[e] = (short)hh; lo[e] = (short)f2bf(a[e] - bf2f(hh));
          unsigned short h2 = f2bf(b2[e]); h[e + 4] = (short)h2; lo[e + 4] = (short)f2bf(b2[e] - bf2f(h2));
        }
        D = mfma16(h, xh[cc], D);
        D = mfma16(h, xl[cc], D);
        D = mfma16(lo, xh[cc], D);
      }
#pragma unroll
      for (int r = 0; r < 4; ++r)
        ob[(size_t)(o0 + g * 4 + r) * N + nb * 64 + nt * 16 + l15] = D[r] + bias[r];
    }
  }
}

extern "C" void kernel_launch(void* const* d_in, const int* in_sizes, int n_in,
                              void* d_out, int out_size, void* d_ws, size_t ws_size,
                              hipStream_t stream) {
  const float* x = (const float*)d_in[0];
  const float* wq = (const float*)d_in[1];
  const float* bq = (const float*)d_in[2];
  const float* wk = (const float*)d_in[3];
  const float* bk = (const float*)d_in[4];
  const float* wv = (const float*)d_in[5];
  const float* bv = (const float*)d_in[6];
  const float* wp = (const float*)d_in[7];
  const float* bp = (const float*)d_in[8];
  float* out = (float*)d_out;
  char* ws = (char*)d_ws;
  // workspace layout (bytes):
  unsigned short* XT = (unsigned short*)(ws + 0);         //  8 MB bf16 [B][N][C]
  unsigned short* QT = (unsigned short*)(ws + 8388608);   //  8 MB bf16 [B][N][C] (scaled by 1/16)
  unsigned short* KT = (unsigned short*)(ws + 16777216);  //  8 MB bf16 [B][N][C]
  unsigned short* V  = (unsigned short*)(ws + 25165824);  //  8 MB bf16 [B][C][N]
  float* OT = (float*)(ws + 33554432);                    // 16 MB f32 [B][N][C]
  float* M  = (float*)(ws + 50331648);                    // 64 KB f32 [B][N]
  float* L  = (float*)(ws + 50397184);                    // 64 KB f32 [B][N]

  hipMemsetAsync(OT, 0, 16777216, stream);
  hipLaunchKernelGGL(k0_transpose, dim3(1024), dim3(256), 0, stream, x, XT);
  hipLaunchKernelGGL(k1_qkv, dim3(256), dim3(256), 0, stream, XT, wq, bq, wk, bk, wv, bv, QT, KT, V);
  hipLaunchKernelGGL(k2_stats, dim3(512), dim3(256), 0, stream, QT, KT, M, L);
  hipLaunchKernelGGL(k2b_scale_v, dim3(4096), dim3(256), 0, stream, V, L);
  hipLaunchKernelGGL(k3_attn, dim3(512), dim3(256), 0, stream, QT, KT, V, M, OT);
  hipLaunchKernelGGL(k4_proj, dim3(256), dim3(256), 0, stream, OT, wp, bp, out);
}